// Round 15
// baseline (332.502 us; speedup 1.0000x reference)
//
#include <hip/hip_runtime.h>

#define HID 10
#define STEPS 512

typedef __attribute__((ext_vector_type(2))) float v2f;
typedef __attribute__((ext_vector_type(4))) float v4f;

// broadcast lane ((lane&0x10)|F) within each 32-lane half -> all lanes of each 16-group
// (one-time use: t=0 peel + epilogue)
template<int F>
static __device__ __forceinline__ float swz(float v) {
    return __int_as_float(__builtin_amdgcn_ds_swizzle(__float_as_int(v), (F << 5) | 0x10));
}

// Lane-parallel fused GRU decoder, 1 feature per lane, EIGHT batches per wave as
// two SKEWED streams (A = blockIdx*8+g, B = +4), grid 1024 = 1 wave/SIMD.
// v14 = R8's structure + R9's register budget (the untried combination):
//   R8 (alternate complete streams; per-stream write->reads in place) had the
//   right skew — A's DS roundtrip sits under B's ~190cyc of compute and vice
//   versa — but ran at VGPR=64 with ~110 live values: spill/remat serialized it.
//   R9 granted 132 VGPR but batched all reads at loop bottom with both streams'
//   dots at the top: first use waited on a just-issued read (roundtrip exposed).
//   Here: R8 loop verbatim + amdgpu_waves_per_eu(1,1) + NAMED tables (v13).
//   v13 also established issue/wave-step ~190cyc is legitimate (trans ops are
//   quarter-rate: 5 x 16cyc), so the only lever left is covering the ~340cyc
//   stall — which this dependency graph does structurally.
// (Round-14 submission never ran: container-level infra failure. Resubmitted.)
__attribute__((amdgpu_waves_per_eu(1, 1)))
__global__ __launch_bounds__(64) void gru_decoder_kernel(
    const float* __restrict__ hidden, const float* __restrict__ w_ih,
    const float* __restrict__ w_hh, const float* __restrict__ b_ih,
    const float* __restrict__ b_hh, const float* __restrict__ l1_w,
    const float* __restrict__ l1_b, const float* __restrict__ l2_w,
    const float* __restrict__ l2_b, float* __restrict__ out)
{
    __shared__ float sWx[640];   // l2_w @ l1_w (64x10)
    __shared__ float sbx[64];    // l2_w @ l1_b + l2_b
    __shared__ float sWgi[300];  // w_ih @ Wx (30x10)
    __shared__ float sbgi[30];   // b_ih + w_ih @ bx
    __shared__ float sWhh[300];  // w_hh copy (t=0 peel + weight build)
    __shared__ float sH[128];    // 8 rows x 16 floats (A: rows 0-3, B: rows 4-7)

    const int lane = threadIdx.x;
    const int f    = lane & 15;
    const int g    = lane >> 4;
    const int bA   = blockIdx.x * 8 + g;
    const int bB   = bA + 4;
    const bool ok  = (f < HID);
    const int fi   = ok ? f : 0;          // clamped index for safe reads

    // ---- preamble: fused weights (fp32, cooperative) ----
    for (int e = lane; e < 640; e += 64) {
        int i = e / 10, j = e - i * 10;
        float acc = 0.f;
        #pragma unroll
        for (int k = 0; k < 10; ++k) acc += l2_w[i * 10 + k] * l1_w[k * 10 + j];
        sWx[e] = acc;
    }
    {
        float acc = l2_b[lane];
        #pragma unroll
        for (int k = 0; k < 10; ++k) acc += l2_w[lane * 10 + k] * l1_b[k];
        sbx[lane] = acc;
    }
    for (int e = lane; e < 300; e += 64) sWhh[e] = w_hh[e];
    __syncthreads();
    for (int e = lane; e < 300; e += 64) {
        int m = e / 10, j = e - m * 10;
        float acc = 0.f;
        for (int k = 0; k < 64; ++k) acc += w_ih[m * 64 + k] * sWx[k * 10 + j];
        sWgi[e] = acc;
    }
    if (lane < 30) {
        float acc = b_ih[lane];
        for (int k = 0; k < 64; ++k) acc += w_ih[lane * 64 + k] * sbx[k];
        sbgi[lane] = acc;
    }
    __syncthreads();

    const float LOG2E = 1.4426950408889634f;
    const float S2    = 2.f * LOG2E;

    // ---- per-lane weights (feature fi), packed across k, NAMED values (shared A/B) ----
    #define MKW(k2)                                                              \
        const int k0_##k2 = 2 * (k2), k1_##k2 = 2 * (k2) + 1;                    \
        const v2f wr##k2 = ok ? v2f{                                             \
            -(sWgi[fi * 10 + k0_##k2] + sWhh[fi * 10 + k0_##k2]) * LOG2E,        \
            -(sWgi[fi * 10 + k1_##k2] + sWhh[fi * 10 + k1_##k2]) * LOG2E}        \
            : v2f{0.f, 0.f};                                                     \
        const v2f wz##k2 = ok ? v2f{                                             \
            -(sWgi[(10 + fi) * 10 + k0_##k2] + sWhh[(10 + fi) * 10 + k0_##k2]) * LOG2E, \
            -(sWgi[(10 + fi) * 10 + k1_##k2] + sWhh[(10 + fi) * 10 + k1_##k2]) * LOG2E} \
            : v2f{0.f, 0.f};                                                     \
        const v2f wi##k2 = ok ? v2f{                                             \
            sWgi[(20 + fi) * 10 + k0_##k2] * S2,                                 \
            sWgi[(20 + fi) * 10 + k1_##k2] * S2} : v2f{0.f, 0.f};                \
        const v2f wh##k2 = ok ? v2f{                                             \
            sWhh[(20 + fi) * 10 + k0_##k2] * S2,                                 \
            sWhh[(20 + fi) * 10 + k1_##k2] * S2} : v2f{0.f, 0.f};                \
        const v2f wo##k2 = ok ? v2f{                                             \
            l1_w[fi * 10 + k0_##k2], l1_w[fi * 10 + k1_##k2]} : v2f{0.f, 0.f};
    MKW(0) MKW(1) MKW(2) MKW(3) MKW(4)
    #undef MKW

    const float br = ok ? -(sbgi[fi] + b_hh[fi]) * LOG2E : 0.f;
    const float bz = ok ? -(sbgi[10 + fi] + b_hh[10 + fi]) * LOG2E : 0.f;
    const float bi = ok ? sbgi[20 + fi] * S2 : 0.f;
    const float bh = ok ? b_hh[20 + fi] * S2 : 0.f;
    const float bo = ok ? l1_b[fi] : 0.f;
    const v2f BR2 = {br, 0.f}, BZ2 = {bz, 0.f}, BI2 = {bi, 0.f},
              BH2 = {bh, 0.f}, BO2 = {bo, 0.f};
    // t=0 peel biases (gi = b_ih only)
    const float br0_ = ok ? -(b_ih[fi] + b_hh[fi]) * LOG2E : 0.f;
    const float bz0_ = ok ? -(b_ih[10 + fi] + b_hh[10 + fi]) * LOG2E : 0.f;
    const float bni0 = ok ? b_ih[20 + fi] * S2 : 0.f;

    // ---- initial h for both streams (f>=10 stays exactly 0) ----
    float hA = ok ? hidden[(size_t)bA * HID + f] : 0.f;
    float hB = ok ? hidden[(size_t)bB * HID + f] : 0.f;

    float* pbA = out + (size_t)bA * (STEPS * HID) + (size_t)(STEPS - 1) * HID + f;
    float* pbB = out + (size_t)bB * (STEPS * HID) + (size_t)(STEPS - 1) * HID + f;
    float* rowA = &sH[g * 16];
    float* rowB = &sH[(4 + g) * 16];

    // ---- t = 0 peel (gi = b_ih only; x_0 = 0) for both streams ----
    auto peel0 = [&](float& h) {
        float ha[10];
        ha[0] = swz<0>(h); ha[1] = swz<1>(h); ha[2] = swz<2>(h);
        ha[3] = swz<3>(h); ha[4] = swz<4>(h); ha[5] = swz<5>(h);
        ha[6] = swz<6>(h); ha[7] = swz<7>(h); ha[8] = swz<8>(h);
        ha[9] = swz<9>(h);
        float pr = 0.f, pz = 0.f, ph = 0.f;
        #pragma unroll
        for (int k = 0; k < 10; ++k) {
            pr += sWhh[fi * 10 + k] * ha[k];
            pz += sWhh[(10 + fi) * 10 + k] * ha[k];
            ph += sWhh[(20 + fi) * 10 + k] * ha[k];
        }
        float vr = br0_ - pr * LOG2E;
        float vz = bz0_ - pz * LOG2E;
        float r = __builtin_amdgcn_rcpf(1.f + __builtin_amdgcn_exp2f(vr));
        float z = __builtin_amdgcn_rcpf(1.f + __builtin_amdgcn_exp2f(vz));
        float y = bni0 + r * (ph * S2 + bh);
        float n = 1.f - 2.f * __builtin_amdgcn_rcpf(1.f + __builtin_amdgcn_exp2f(y));
        h = ok ? (n + z * (h - n)) : 0.f;
    };
    peel0(hA);
    peel0(hB);

    // ---- pre-loop stage: write h_1, read gather regs for both streams ----
    rowA[f] = hA;
    rowB[f] = hB;
    __builtin_amdgcn_wave_barrier();      // one-time ordering (outside hot loop)
    v4f qA0 = *(const v4f*)(rowA); v4f qA1 = *(const v4f*)(rowA + 4);
    v2f qA2 = *(const v2f*)(rowA + 8);
    v4f qB0 = *(const v4f*)(rowB); v4f qB1 = *(const v4f*)(rowB + 4);
    v2f qB2 = *(const v2f*)(rowB + 8);

    // one full GRU step for one stream from its gathered regs (h_t) -> h_{t+1}, o_{t-1}
    auto gru_step = [&](v4f q0, v4f q1, v2f q2, float& h, float& o) {
        v2f h2_0 = __builtin_shufflevector(q0, q0, 0, 1);
        v2f h2_1 = __builtin_shufflevector(q0, q0, 2, 3);
        v2f h2_2 = __builtin_shufflevector(q1, q1, 0, 1);
        v2f h2_3 = __builtin_shufflevector(q1, q1, 2, 3);
        v2f h2_4 = q2;
        v2f ar = wr0 * h2_0 + BR2;
        v2f az = wz0 * h2_0 + BZ2;
        v2f ai = wi0 * h2_0 + BI2;
        v2f ah = wh0 * h2_0 + BH2;
        v2f ao = wo0 * h2_0 + BO2;
        ar += wr1 * h2_1; az += wz1 * h2_1; ai += wi1 * h2_1;
        ah += wh1 * h2_1; ao += wo1 * h2_1;
        ar += wr2 * h2_2; az += wz2 * h2_2; ai += wi2 * h2_2;
        ah += wh2 * h2_2; ao += wo2 * h2_2;
        ar += wr3 * h2_3; az += wz3 * h2_3; ai += wi3 * h2_3;
        ah += wh3 * h2_3; ao += wo3 * h2_3;
        ar += wr4 * h2_4; az += wz4 * h2_4; ai += wi4 * h2_4;
        ah += wh4 * h2_4; ao += wo4 * h2_4;
        float arx = ar.x + ar.y;
        float azx = az.x + az.y;
        float aix = ai.x + ai.y;
        float ahx = ah.x + ah.y;
        o = ao.x + ao.y;                  // = l1(h_t) = o_{t-1}
        // fused z/n update, single rcp: h' = (ez(en-1)+h(en+1)) / ((en+1)(1+ez))
        float er = __builtin_amdgcn_exp2f(arx);
        float r  = __builtin_amdgcn_rcpf(1.f + er);
        float ez = __builtin_amdgcn_exp2f(azx);
        float y  = __builtin_fmaf(r, ahx, aix);
        float en = __builtin_amdgcn_exp2f(y);
        float p  = en * ez;
        float tt = h - ez;
        float u  = p + tt;
        float num = __builtin_fmaf(h, en, u);
        float v   = en + ez;
        float den = (p + v) + 1.f;
        h = num * __builtin_amdgcn_rcpf(den);   // padded lanes: h stays 0
    };

    // ---- t = 1 .. 511 : skewed streams — A's DS roundtrip hides under B's
    //      compute and vice versa (enforced by the dependency graph itself) ----
    #pragma unroll 1
    for (int t = 1; t < STEPS; ++t) {
        float oA, oB;
        // stream A: compute (waits on qA read issued last iteration, already
        // covered by stream B's work), then write+read-issue for next step
        gru_step(qA0, qA1, qA2, hA, oA);
        rowA[f] = hA;                          // aliasing pins write->read order
        qA0 = *(const v4f*)(rowA);
        qA1 = *(const v4f*)(rowA + 4);
        qA2 = *(const v2f*)(rowA + 8);
        if (ok) pbA[0] = oA;                   // fills A's roundtrip window
        pbA -= HID;
        // stream B: its compute covers A's roundtrip; its own roundtrip is
        // covered by next iteration's stream-A compute
        gru_step(qB0, qB1, qB2, hB, oB);
        rowB[f] = hB;
        qB0 = *(const v4f*)(rowB);
        qB1 = *(const v4f*)(rowB + 4);
        qB2 = *(const v2f*)(rowB + 8);
        if (ok) pbB[0] = oB;
        pbB -= HID;
    }

    // ---- epilogue: o_511 = l1(h_512) at position 0 (qA/qB hold h_512) ----
    {
        v2f aoA = wo0 * __builtin_shufflevector(qA0, qA0, 0, 1) + BO2;
        aoA += wo1 * __builtin_shufflevector(qA0, qA0, 2, 3);
        aoA += wo2 * __builtin_shufflevector(qA1, qA1, 0, 1);
        aoA += wo3 * __builtin_shufflevector(qA1, qA1, 2, 3);
        aoA += wo4 * qA2;
        v2f aoB = wo0 * __builtin_shufflevector(qB0, qB0, 0, 1) + BO2;
        aoB += wo1 * __builtin_shufflevector(qB0, qB0, 2, 3);
        aoB += wo2 * __builtin_shufflevector(qB1, qB1, 0, 1);
        aoB += wo3 * __builtin_shufflevector(qB1, qB1, 2, 3);
        aoB += wo4 * qB2;
        if (ok) { pbA[0] = aoA.x + aoA.y; pbB[0] = aoB.x + aoB.y; }
    }
}

extern "C" void kernel_launch(void* const* d_in, const int* in_sizes, int n_in,
                              void* d_out, int out_size, void* d_ws, size_t ws_size,
                              hipStream_t stream) {
    (void)in_sizes; (void)n_in; (void)d_ws; (void)ws_size; (void)out_size;
    dim3 grid(1024), block(64);   // 8 batches/wave (2 skewed streams), 1 wave/SIMD
    gru_decoder_kernel<<<grid, block, 0, stream>>>(
        (const float*)d_in[0], (const float*)d_in[1], (const float*)d_in[2],
        (const float*)d_in[3], (const float*)d_in[4], (const float*)d_in[5],
        (const float*)d_in[6], (const float*)d_in[7], (const float*)d_in[8],
        (float*)d_out);
}

// Round 16
// 283.159 us; speedup vs baseline: 1.1743x; 1.1743x over previous
//
#include <hip/hip_runtime.h>

#define HID 10
#define STEPS 512

typedef __attribute__((ext_vector_type(2))) float v2f;
typedef __attribute__((ext_vector_type(4))) float v4f;

// broadcast lane ((lane&0x10)|F) within each 32-lane half -> all lanes of each 16-group
// (one-time use: t=0 peel + epilogue)
template<int F>
static __device__ __forceinline__ float swz(float v) {
    return __int_as_float(__builtin_amdgcn_ds_swizzle(__float_as_int(v), (F << 5) | 0x10));
}

// Lane-parallel fused GRU decoder, 1 feature per lane, 4 batches per wave.
//   batch = blockIdx*4 + (lane>>4); f = lane&15 (f>=10: zero-padded, stores masked)
// v16 = v13 (2 waves/SIMD, 157us) with the o-dot moved INTO the LDS-roundtrip
// window. Session evidence: 2-wave variants cluster at 154-157us (HW TLP hides
// each wave's trans-tail bubbles in the other's issue); 1-wave variants at
// 196-210us (single PC exposes every bubble; R8/R9/R14 all falsified).
// v13's loop had write->read->wait at top with EVERYTHING after the wait
// dependent on the incoming q -> full ~140cyc roundtrip exposed. The o-dot
// (5 pk_fma + fold + store, ~35cyc) depends only on the CURRENT q. New order:
//   gates(q) -> tail -> h; write h; issue next reads; o-dot from old q; store.
// Gather regs ping-pong via explicit 2x unroll + odd-iteration peel (no movs).
__attribute__((amdgpu_waves_per_eu(2, 2)))
__global__ __launch_bounds__(64) void gru_decoder_kernel(
    const float* __restrict__ hidden, const float* __restrict__ w_ih,
    const float* __restrict__ w_hh, const float* __restrict__ b_ih,
    const float* __restrict__ b_hh, const float* __restrict__ l1_w,
    const float* __restrict__ l1_b, const float* __restrict__ l2_w,
    const float* __restrict__ l2_b, float* __restrict__ out)
{
    __shared__ float sWx[640];   // l2_w @ l1_w (64x10)
    __shared__ float sbx[64];    // l2_w @ l1_b + l2_b
    __shared__ float sWgi[300];  // w_ih @ Wx (30x10)
    __shared__ float sbgi[30];   // b_ih + w_ih @ bx
    __shared__ float sWhh[300];  // w_hh copy (t=0 peel + weight build)
    __shared__ float sH[64];     // 4 groups x 16-float rows (gather staging)

    const int lane = threadIdx.x;
    const int f    = lane & 15;
    const int g    = lane >> 4;
    const int b    = blockIdx.x * 4 + g;
    const bool ok  = (f < HID);
    const int fi   = ok ? f : 0;          // clamped index for safe reads

    // ---- preamble: fused weights (fp32, cooperative) ----
    for (int e = lane; e < 640; e += 64) {
        int i = e / 10, j = e - i * 10;
        float acc = 0.f;
        #pragma unroll
        for (int k = 0; k < 10; ++k) acc += l2_w[i * 10 + k] * l1_w[k * 10 + j];
        sWx[e] = acc;
    }
    {
        float acc = l2_b[lane];
        #pragma unroll
        for (int k = 0; k < 10; ++k) acc += l2_w[lane * 10 + k] * l1_b[k];
        sbx[lane] = acc;
    }
    for (int e = lane; e < 300; e += 64) sWhh[e] = w_hh[e];
    __syncthreads();
    for (int e = lane; e < 300; e += 64) {
        int m = e / 10, j = e - m * 10;
        float acc = 0.f;
        for (int k = 0; k < 64; ++k) acc += w_ih[m * 64 + k] * sWx[k * 10 + j];
        sWgi[e] = acc;
    }
    if (lane < 30) {
        float acc = b_ih[lane];
        for (int k = 0; k < 64; ++k) acc += w_ih[lane * 64 + k] * sbx[k];
        sbgi[lane] = acc;
    }
    __syncthreads();

    const float LOG2E = 1.4426950408889634f;
    const float S2    = 2.f * LOG2E;

    // ---- per-lane weights (feature fi), packed across k, NAMED values ----
    #define MKW(k2)                                                              \
        const int k0_##k2 = 2 * (k2), k1_##k2 = 2 * (k2) + 1;                    \
        const v2f wr##k2 = ok ? v2f{                                             \
            -(sWgi[fi * 10 + k0_##k2] + sWhh[fi * 10 + k0_##k2]) * LOG2E,        \
            -(sWgi[fi * 10 + k1_##k2] + sWhh[fi * 10 + k1_##k2]) * LOG2E}        \
            : v2f{0.f, 0.f};                                                     \
        const v2f wz##k2 = ok ? v2f{                                             \
            -(sWgi[(10 + fi) * 10 + k0_##k2] + sWhh[(10 + fi) * 10 + k0_##k2]) * LOG2E, \
            -(sWgi[(10 + fi) * 10 + k1_##k2] + sWhh[(10 + fi) * 10 + k1_##k2]) * LOG2E} \
            : v2f{0.f, 0.f};                                                     \
        const v2f wi##k2 = ok ? v2f{                                             \
            sWgi[(20 + fi) * 10 + k0_##k2] * S2,                                 \
            sWgi[(20 + fi) * 10 + k1_##k2] * S2} : v2f{0.f, 0.f};                \
        const v2f wh##k2 = ok ? v2f{                                             \
            sWhh[(20 + fi) * 10 + k0_##k2] * S2,                                 \
            sWhh[(20 + fi) * 10 + k1_##k2] * S2} : v2f{0.f, 0.f};                \
        const v2f wo##k2 = ok ? v2f{                                             \
            l1_w[fi * 10 + k0_##k2], l1_w[fi * 10 + k1_##k2]} : v2f{0.f, 0.f};
    MKW(0) MKW(1) MKW(2) MKW(3) MKW(4)
    #undef MKW

    const float br = ok ? -(sbgi[fi] + b_hh[fi]) * LOG2E : 0.f;
    const float bz = ok ? -(sbgi[10 + fi] + b_hh[10 + fi]) * LOG2E : 0.f;
    const float bi = ok ? sbgi[20 + fi] * S2 : 0.f;
    const float bh = ok ? b_hh[20 + fi] * S2 : 0.f;
    const float bo = ok ? l1_b[fi] : 0.f;
    const v2f BR2 = {br, 0.f}, BZ2 = {bz, 0.f}, BI2 = {bi, 0.f},
              BH2 = {bh, 0.f}, BO2 = {bo, 0.f};
    // t=0 peel biases (gi = b_ih only)
    const float br0_ = ok ? -(b_ih[fi] + b_hh[fi]) * LOG2E : 0.f;
    const float bz0_ = ok ? -(b_ih[10 + fi] + b_hh[10 + fi]) * LOG2E : 0.f;
    const float bni0 = ok ? b_ih[20 + fi] * S2 : 0.f;

    // ---- initial h (one feature per lane; f>=10 stays exactly 0) ----
    float h = ok ? hidden[(size_t)b * HID + f] : 0.f;

    float* pb = out + (size_t)b * (STEPS * HID) + (size_t)(STEPS - 1) * HID + f;
    float* sHrow = &sH[g * 16];

    // ---- t = 0 peeled: gi = b_ih only (x_0 = 0); raw w_hh dots from LDS ----
    // Produces h1. o_0 = l1(h1) is stored by the first loop iteration.
    {
        float ha[10];
        ha[0] = swz<0>(h); ha[1] = swz<1>(h); ha[2] = swz<2>(h);
        ha[3] = swz<3>(h); ha[4] = swz<4>(h); ha[5] = swz<5>(h);
        ha[6] = swz<6>(h); ha[7] = swz<7>(h); ha[8] = swz<8>(h);
        ha[9] = swz<9>(h);
        float pr = 0.f, pz = 0.f, ph = 0.f;
        #pragma unroll
        for (int k = 0; k < 10; ++k) {
            pr += sWhh[fi * 10 + k] * ha[k];
            pz += sWhh[(10 + fi) * 10 + k] * ha[k];
            ph += sWhh[(20 + fi) * 10 + k] * ha[k];
        }
        float vr = br0_ - pr * LOG2E;
        float vz = bz0_ - pz * LOG2E;
        float r = __builtin_amdgcn_rcpf(1.f + __builtin_amdgcn_exp2f(vr));
        float z = __builtin_amdgcn_rcpf(1.f + __builtin_amdgcn_exp2f(vz));
        float y = bni0 + r * (ph * S2 + bh);
        float n = 1.f - 2.f * __builtin_amdgcn_rcpf(1.f + __builtin_amdgcn_exp2f(y));
        h = ok ? (n + z * (h - n)) : 0.f;
    }

    // ---- prologue: stage h_1 and issue the first gather ----
    sHrow[f] = h;
    __builtin_amdgcn_wave_barrier();
    __builtin_amdgcn_sched_barrier(0);
    v4f p0 = *(const v4f*)(sHrow);
    v4f p1 = *(const v4f*)(sHrow + 4);
    v2f p2 = *(const v2f*)(sHrow + 8);
    v4f r0, r1; v2f r2;

    // One iteration: gates from (a0,a1,a2) -> new h; write h; issue reads into
    // (n0,n1,n2); THEN o-dot from the old (a0,a1,a2) + store — the o-dot and
    // store fill the LDS write->read roundtrip window.
    #define STEP(a0, a1, a2, n0, n1, n2)                                        \
    {                                                                           \
        v2f h2_0 = __builtin_shufflevector(a0, a0, 0, 1);                       \
        v2f h2_1 = __builtin_shufflevector(a0, a0, 2, 3);                       \
        v2f h2_2 = __builtin_shufflevector(a1, a1, 0, 1);                       \
        v2f h2_3 = __builtin_shufflevector(a1, a1, 2, 3);                       \
        v2f h2_4 = a2;                                                          \
        v2f ar = wr0 * h2_0 + BR2;                                              \
        v2f az = wz0 * h2_0 + BZ2;                                              \
        v2f ai = wi0 * h2_0 + BI2;                                              \
        v2f ah = wh0 * h2_0 + BH2;                                              \
        ar += wr1 * h2_1; az += wz1 * h2_1; ai += wi1 * h2_1; ah += wh1 * h2_1; \
        ar += wr2 * h2_2; az += wz2 * h2_2; ai += wi2 * h2_2; ah += wh2 * h2_2; \
        ar += wr3 * h2_3; az += wz3 * h2_3; ai += wi3 * h2_3; ah += wh3 * h2_3; \
        ar += wr4 * h2_4; az += wz4 * h2_4; ai += wi4 * h2_4; ah += wh4 * h2_4; \
        float arx = ar.x + ar.y;                                                \
        float azx = az.x + az.y;                                                \
        float aix = ai.x + ai.y;                                                \
        float ahx = ah.x + ah.y;                                                \
        float er = __builtin_amdgcn_exp2f(arx);                                 \
        float rr = __builtin_amdgcn_rcpf(1.f + er);                             \
        float ez = __builtin_amdgcn_exp2f(azx);                                 \
        float y  = __builtin_fmaf(rr, ahx, aix);                                \
        float en = __builtin_amdgcn_exp2f(y);                                   \
        float pp = en * ez;                                                     \
        float u  = pp + (h - ez);                                               \
        float num = __builtin_fmaf(h, en, u);                                   \
        float den = (pp + (en + ez)) + 1.f;                                     \
        h = num * __builtin_amdgcn_rcpf(den);   /* padded lanes: h stays 0 */   \
        sHrow[f] = h;                                                           \
        __builtin_amdgcn_wave_barrier();                                        \
        __builtin_amdgcn_sched_barrier(0);                                      \
        n0 = *(const v4f*)(sHrow);                                              \
        n1 = *(const v4f*)(sHrow + 4);                                          \
        n2 = *(const v2f*)(sHrow + 8);                                          \
        /* o-dot from OLD gather regs: fills the roundtrip window */            \
        v2f ao = wo0 * h2_0 + BO2;                                              \
        ao += wo1 * h2_1;                                                       \
        ao += wo2 * h2_2;                                                       \
        ao += wo3 * h2_3;                                                       \
        ao += wo4 * h2_4;                                                       \
        float o = ao.x + ao.y;            /* = l1(h_t) = o_{t-1} */             \
        if (ok) pb[0] = o;                                                      \
        pb -= HID;                                                              \
    }

    // ---- t = 1 .. 510 (255 ping-pong pairs), then t = 511 peeled ----
    #pragma unroll 1
    for (int t = 1; t + 1 < STEPS; t += 2) {
        STEP(p0, p1, p2, r0, r1, r2);
        STEP(r0, r1, r2, p0, p1, p2);
    }
    STEP(p0, p1, p2, r0, r1, r2);       // t = 511; r now holds gather of h_512
    #undef STEP

    // ---- epilogue: o_511 = l1(h_512) at position 0 ----
    {
        v2f ao = wo0 * __builtin_shufflevector(r0, r0, 0, 1) + BO2;
        ao += wo1 * __builtin_shufflevector(r0, r0, 2, 3);
        ao += wo2 * __builtin_shufflevector(r1, r1, 0, 1);
        ao += wo3 * __builtin_shufflevector(r1, r1, 2, 3);
        ao += wo4 * r2;
        if (ok) pb[0] = ao.x + ao.y;
    }
}

extern "C" void kernel_launch(void* const* d_in, const int* in_sizes, int n_in,
                              void* d_out, int out_size, void* d_ws, size_t ws_size,
                              hipStream_t stream) {
    (void)in_sizes; (void)n_in; (void)d_ws; (void)ws_size; (void)out_size;
    dim3 grid(2048), block(64);   // 4 batches/wave, 2048 waves -> 2 waves per SIMD
    gru_decoder_kernel<<<grid, block, 0, stream>>>(
        (const float*)d_in[0], (const float*)d_in[1], (const float*)d_in[2],
        (const float*)d_in[3], (const float*)d_in[4], (const float*)d_in[5],
        (const float*)d_in[6], (const float*)d_in[7], (const float*)d_in[8],
        (float*)d_out);
}